// Round 6
// baseline (274.708 us; speedup 1.0000x reference)
//
#include <hip/hip_runtime.h>
#include <math.h>

#define BATCH 2
#define SEQ   2048
#define DM    1024
#define DI    2048
#define NST   16
#define MT    (BATCH*SEQ)   // 4096
#define CHK   64            // chunks along T
#define LCH   (SEQ/CHK)     // 32 steps per chunk

typedef __attribute__((ext_vector_type(8))) short  bf16x8;
typedef __attribute__((ext_vector_type(4))) float  f32x4;

static __device__ __forceinline__ unsigned short f2bf(float f) {
  unsigned u = __float_as_uint(f);
  u += 0x7fff + ((u >> 16) & 1);          // RNE
  return (unsigned short)(u >> 16);
}
static __device__ __forceinline__ float bf2f(unsigned short h) {
  return __uint_as_float(((unsigned)h) << 16);
}

// ---------------------------------------------------------------------------
// fp32 -> bf16 bulk convert (float4 in, ushort4 out)
// ---------------------------------------------------------------------------
__global__ __launch_bounds__(256) void conv_bf16_kernel(
    const float* __restrict__ src, unsigned short* __restrict__ dst, int n4)
{
  int i = blockIdx.x * 256 + threadIdx.x;
  if (i < n4) {
    float4 v = ((const float4*)src)[i];
    ushort4 o;
    o.x = f2bf(v.x); o.y = f2bf(v.y); o.z = f2bf(v.z); o.w = f2bf(v.w);
    ((ushort4*)dst)[i] = o;
  }
}

// ---------------------------------------------------------------------------
// bf16 MFMA GEMM v2: C(M,N) = act(A(M,K) @ B(N,K)^T + bias(N))
// Tile 128 x BN, BK=64, 256 thr = 4 waves (2x2); double-buffered LDS with
// next-tile prefetch before compute; one barrier per K-tile.
// ACT: 0 = none, 1 = softplus.
// ---------------------------------------------------------------------------
template<int BN, bool OUT_BF16, int LDC, int ACT>
__global__ __launch_bounds__(256, 2) void gemm2_kernel(
    const unsigned short* __restrict__ A,
    const unsigned short* __restrict__ B,
    const float* __restrict__ bias,
    void* __restrict__ Cout, int K, int nbx)
{
  constexpr int NJ = BN / 32;               // N-frags per wave
  __shared__ unsigned short Abuf[2][2][128*32];   // [buf][k-half][row*32+col]
  __shared__ unsigned short Bbuf[2][2][BN*32];

  // XCD-aware block swizzle (grid % 8 == 0)
  const int nwg = gridDim.x;
  const int cpx = nwg >> 3;
  const int bid = blockIdx.x;
  const int swz = (bid & 7) * cpx + (bid >> 3);
  const int bx = swz % nbx;
  const int by = swz / nbx;

  const int tid  = threadIdx.x;
  const int lane = tid & 63;
  const int wid  = tid >> 6;
  const int wr   = wid >> 1;    // wave row (0..1)
  const int wc   = wid & 1;     // wave col (0..1)
  const int lr    = lane >> 2;  // staging: row within 16-row group
  const int lslot = lane & 3;   // staging: 16B slot within 32-elem row

  f32x4 zero = {0.f, 0.f, 0.f, 0.f};
  f32x4 acc[4][NJ];
#pragma unroll
  for (int i = 0; i < 4; ++i)
#pragma unroll
    for (int j = 0; j < NJ; ++j) acc[i][j] = zero;

  const size_t arow0 = (size_t)by * 128;
  const size_t brow0 = (size_t)bx * BN;
  const int NT = K >> 6;        // K-tiles of 64

  auto STAGE = [&](int buf, int k0) {
#pragma unroll
    for (int half = 0; half < 2; ++half) {
#pragma unroll
      for (int i = 0; i < 2; ++i) {         // A: 8 groups of 16 rows
        const int Rb = (wid + i*4) * 16;
        const int r  = Rb + lr;
        const int c8 = lslot ^ ((r >> 1) & 3);
        const unsigned short* ga = A + (arow0 + r)*(size_t)K + k0 + half*32 + c8*8;
        __builtin_amdgcn_global_load_lds(
            (const __attribute__((address_space(1))) void*)ga,
            (__attribute__((address_space(3))) void*)(&Abuf[buf][half][Rb*32]),
            16, 0, 0);
      }
#pragma unroll
      for (int i = 0; i < BN/64; ++i) {     // B: BN/16 groups
        const int Rb = (wid + i*4) * 16;
        const int r  = Rb + lr;
        const int c8 = lslot ^ ((r >> 1) & 3);
        const unsigned short* gb = B + (brow0 + r)*(size_t)K + k0 + half*32 + c8*8;
        __builtin_amdgcn_global_load_lds(
            (const __attribute__((address_space(1))) void*)gb,
            (__attribute__((address_space(3))) void*)(&Bbuf[buf][half][Rb*32]),
            16, 0, 0);
      }
    }
  };

  STAGE(0, 0);
  __syncthreads();

  const int lrow = lane & 15, k8 = lane >> 4;
  int cur = 0;
  for (int kt = 0; kt < NT; ++kt) {
    if (kt + 1 < NT) STAGE(cur ^ 1, (kt + 1) * 64);

#pragma unroll
    for (int half = 0; half < 2; ++half) {
      bf16x8 af[4], bfr[NJ];
#pragma unroll
      for (int mi = 0; mi < 4; ++mi) {
        const int r = wr*64 + mi*16 + lrow;
        af[mi] = *(const bf16x8*)&Abuf[cur][half][r*32 + (k8 ^ ((r >> 1) & 3))*8];
      }
#pragma unroll
      for (int nj = 0; nj < NJ; ++nj) {
        const int r = wc*(BN/2) + nj*16 + lrow;
        bfr[nj] = *(const bf16x8*)&Bbuf[cur][half][r*32 + (k8 ^ ((r >> 1) & 3))*8];
      }
      __builtin_amdgcn_s_setprio(1);
#pragma unroll
      for (int mi = 0; mi < 4; ++mi)
#pragma unroll
        for (int nj = 0; nj < NJ; ++nj)
          acc[mi][nj] = __builtin_amdgcn_mfma_f32_16x16x32_bf16(
                            af[mi], bfr[nj], acc[mi][nj], 0, 0, 0);
      __builtin_amdgcn_s_setprio(0);
    }
    __syncthreads();
    cur ^= 1;
  }

  const int lcol = lane & 15, lrq = lane >> 4;
#pragma unroll
  for (int nj = 0; nj < NJ; ++nj) {
    const int colg = bx*BN + wc*(BN/2) + nj*16 + lcol;
    const float bv = bias[colg];
#pragma unroll
    for (int mi = 0; mi < 4; ++mi) {
      const int rowg = by*128 + wr*64 + mi*16 + lrq*4;
#pragma unroll
      for (int q = 0; q < 4; ++q) {
        float v = acc[mi][nj][q] + bv;
        if constexpr (ACT == 1)
          v = (v > 20.f) ? v : log1pf(expf(v));
        if constexpr (OUT_BF16)
          ((unsigned short*)Cout)[(size_t)(rowg + q)*LDC + colg] = f2bf(v);
        else
          ((float*)Cout)[(size_t)(rowg + q)*LDC + colg] = v;
      }
    }
  }
}

// ---------------------------------------------------------------------------
// dbc = x @ W_x^T + b_x via MFMA.  Cols 0..63 (delta_raw) -> draw_bf (bf16),
// cols 64..95 (B,C) -> dbc fp32.
// ---------------------------------------------------------------------------
__global__ __launch_bounds__(256) void dbc_mfma_kernel(
    const unsigned short* __restrict__ A,     // ui_bf
    const unsigned short* __restrict__ Bw,    // wx_bf
    const float* __restrict__ bx,
    float* __restrict__ dbc,
    unsigned short* __restrict__ draw_bf)
{
  __shared__ unsigned short Abuf[64*32];   // 4 KiB
  __shared__ unsigned short Bbuf[96*32];   // 6 KiB

  const int tid  = threadIdx.x;
  const int lane = tid & 63;
  const int wid  = tid >> 6;
  const int lr    = lane >> 2;
  const int lslot = lane & 3;
  const size_t arow0 = (size_t)blockIdx.x * 64;

  f32x4 zero = {0.f, 0.f, 0.f, 0.f};
  f32x4 acc[6];
#pragma unroll
  for (int j = 0; j < 6; ++j) acc[j] = zero;

  for (int k0 = 0; k0 < DI; k0 += 32) {
    {
      const int Rb = wid*16;
      const int r  = Rb + lr;
      const int c8 = lslot ^ ((r >> 1) & 3);
      const unsigned short* ga = A + (arow0 + r)*4096 + k0 + c8*8;
      __builtin_amdgcn_global_load_lds(
          (const __attribute__((address_space(1))) void*)ga,
          (__attribute__((address_space(3))) void*)(Abuf + Rb*32), 16, 0, 0);
    }
    if (wid < 3) {
#pragma unroll
      for (int i = 0; i < 2; ++i) {
        const int Rb = wid*32 + i*16;
        const int r  = Rb + lr;
        const int c8 = lslot ^ ((r >> 1) & 3);
        const unsigned short* gb = Bw + (size_t)r*DI + k0 + c8*8;
        __builtin_amdgcn_global_load_lds(
            (const __attribute__((address_space(1))) void*)gb,
            (__attribute__((address_space(3))) void*)(Bbuf + Rb*32), 16, 0, 0);
      }
    }
    __syncthreads();

    const int lrow = lane & 15, k8 = lane >> 4;
    const int ra = wid*16 + lrow;
    bf16x8 af = *(const bf16x8*)&Abuf[ra*32 + (k8 ^ ((ra >> 1) & 3))*8];
#pragma unroll
    for (int nj = 0; nj < 6; ++nj) {
      const int rb = nj*16 + lrow;
      bf16x8 bf_ = *(const bf16x8*)&Bbuf[rb*32 + (k8 ^ ((rb >> 1) & 3))*8];
      acc[nj] = __builtin_amdgcn_mfma_f32_16x16x32_bf16(af, bf_, acc[nj], 0, 0, 0);
    }
    __syncthreads();
  }

  const int lcol = lane & 15, lrq = lane >> 4;
  const int rowg = (int)arow0 + wid*16 + lrq*4;
#pragma unroll
  for (int nj = 0; nj < 6; ++nj) {
    const int colg = nj*16 + lcol;
    const float bv = bx[colg];
#pragma unroll
    for (int q = 0; q < 4; ++q) {
      float v = acc[nj][q] + bv;
      if (nj < 4)
        draw_bf[(size_t)(rowg + q)*64 + colg] = f2bf(v);
      else
        dbc[(size_t)(rowg + q)*96 + colg] = v;
    }
  }
}

// ---------------------------------------------------------------------------
// Chunked scan, pass A: local scan from h=0; emits P = exp(A*sum dt), S = h_end
// grid = BATCH*CHK*DI/256 = 1024; (b,c) derived from blockIdx -> uniform
// dbc row pointers -> scalar loads.
// ---------------------------------------------------------------------------
__global__ __launch_bounds__(256) void scanA_kernel(
    const unsigned short* __restrict__ uib,
    const float* __restrict__ dbc,
    const unsigned short* __restrict__ delta_bf,
    const float* __restrict__ A_log,
    float* __restrict__ P,
    float* __restrict__ S)
{
  const int bid = blockIdx.x;
  const int d   = (bid & 7)*256 + threadIdx.x;
  const int c   = (bid >> 3) & (CHK-1);
  const int b   = bid >> 9;

  float A2[NST];   // -exp(A_log) * log2(e)
  {
    const float4* ap = (const float4*)(A_log + (size_t)d*NST);
#pragma unroll
    for (int q = 0; q < 4; ++q) {
      float4 v = ap[q];
      A2[q*4+0] = -1.44269504f*expf(v.x); A2[q*4+1] = -1.44269504f*expf(v.y);
      A2[q*4+2] = -1.44269504f*expf(v.z); A2[q*4+3] = -1.44269504f*expf(v.w);
    }
  }

  float h[NST];
#pragma unroll
  for (int nn = 0; nn < NST; ++nn) h[nn] = 0.f;
  float sdt = 0.f;

  const int t0 = c * LCH;
  const unsigned short* dptr = delta_bf + ((size_t)b*SEQ + t0)*DI + d;
  const unsigned short* xptr = uib      + ((size_t)b*SEQ + t0)*4096 + d;
  const float* bptr          = dbc      + ((size_t)b*SEQ + t0)*96 + 64;

  float dt = bf2f(dptr[0]);
  float xv = bf2f(xptr[0]);
  float4 Bv0 = *(const float4*)(bptr + 0);
  float4 Bv1 = *(const float4*)(bptr + 4);
  float4 Bv2 = *(const float4*)(bptr + 8);
  float4 Bv3 = *(const float4*)(bptr + 12);

  for (int t = 0; t < LCH; ++t) {
    const float dtc = dt, xvc = xv;
    float Bc[NST] = {Bv0.x,Bv0.y,Bv0.z,Bv0.w, Bv1.x,Bv1.y,Bv1.z,Bv1.w,
                     Bv2.x,Bv2.y,Bv2.z,Bv2.w, Bv3.x,Bv3.y,Bv3.z,Bv3.w};
    if (t + 1 < LCH) {
      const size_t tn = (size_t)(t+1);
      dt = bf2f(dptr[tn*DI]);
      xv = bf2f(xptr[tn*4096]);
      const float* bp = bptr + tn*96;
      Bv0 = *(const float4*)(bp + 0);
      Bv1 = *(const float4*)(bp + 4);
      Bv2 = *(const float4*)(bp + 8);
      Bv3 = *(const float4*)(bp + 12);
    }
    sdt += dtc;
    const float xdt = xvc * dtc;
#pragma unroll
    for (int nn = 0; nn < NST; ++nn) {
      float dA = exp2f(dtc * A2[nn]);
      h[nn] = h[nn]*dA + xdt*Bc[nn];
    }
  }

  float* Pp = P + (((size_t)b*CHK + c)*DI + d)*NST;
  float* Sp = S + (((size_t)b*CHK + c)*DI + d)*NST;
#pragma unroll
  for (int q = 0; q < 4; ++q) {
    float4 pv = { exp2f(A2[q*4+0]*sdt), exp2f(A2[q*4+1]*sdt),
                  exp2f(A2[q*4+2]*sdt), exp2f(A2[q*4+3]*sdt) };
    float4 sv = { h[q*4+0], h[q*4+1], h[q*4+2], h[q*4+3] };
    *(float4*)(Pp + q*4) = pv;
    *(float4*)(Sp + q*4) = sv;
  }
}

// ---------------------------------------------------------------------------
// Chunked scan, pass B: inter-chunk scan; S replaced by carry-in state.
// ---------------------------------------------------------------------------
__global__ __launch_bounds__(256) void scanB_kernel(
    const float* __restrict__ P, float* __restrict__ S)
{
  const int gid = blockIdx.x*256 + threadIdx.x;
  const int n4 = gid & 3;
  const int d  = (gid >> 2) & (DI-1);
  const int b  = gid >> 13;

  float4 h = {0.f, 0.f, 0.f, 0.f};
  for (int c = 0; c < CHK; ++c) {
    const size_t idx = (((size_t)b*CHK + c)*DI + d)*NST + n4*4;
    float4 p = *(const float4*)(P + idx);
    float4 s = *(const float4*)(S + idx);
    *(float4*)(S + idx) = h;
    h.x = h.x*p.x + s.x;
    h.y = h.y*p.y + s.y;
    h.z = h.z*p.z + s.z;
    h.w = h.w*p.w + s.w;
  }
}

// ---------------------------------------------------------------------------
// Chunked scan, pass C: seeded local scan; y + skip + SiLU gate -> y_bf (bf16)
// ---------------------------------------------------------------------------
__global__ __launch_bounds__(256) void scanC_kernel(
    const unsigned short* __restrict__ uib,
    const float* __restrict__ dbc,
    const unsigned short* __restrict__ delta_bf,
    const float* __restrict__ A_log,
    const float* __restrict__ Dp,
    const float* __restrict__ S,
    unsigned short* __restrict__ y_bf)
{
  const int bid = blockIdx.x;
  const int d   = (bid & 7)*256 + threadIdx.x;
  const int c   = (bid >> 3) & (CHK-1);
  const int b   = bid >> 9;

  float A2[NST];
  {
    const float4* ap = (const float4*)(A_log + (size_t)d*NST);
#pragma unroll
    for (int q = 0; q < 4; ++q) {
      float4 v = ap[q];
      A2[q*4+0] = -1.44269504f*expf(v.x); A2[q*4+1] = -1.44269504f*expf(v.y);
      A2[q*4+2] = -1.44269504f*expf(v.z); A2[q*4+3] = -1.44269504f*expf(v.w);
    }
  }
  const float Dv = Dp[d];

  float h[NST];
  {
    const float* Sp = S + (((size_t)b*CHK + c)*DI + d)*NST;
#pragma unroll
    for (int q = 0; q < 4; ++q) {
      float4 sv = *(const float4*)(Sp + q*4);
      h[q*4+0] = sv.x; h[q*4+1] = sv.y; h[q*4+2] = sv.z; h[q*4+3] = sv.w;
    }
  }

  const int t0 = c * LCH;
  const unsigned short* dptr = delta_bf + ((size_t)b*SEQ + t0)*DI + d;
  const unsigned short* xptr = uib      + ((size_t)b*SEQ + t0)*4096 + d;
  const float* cptr          = dbc      + ((size_t)b*SEQ + t0)*96;
  unsigned short* yp         = y_bf     + ((size_t)b*SEQ + t0)*DI + d;

  float dt = bf2f(dptr[0]);
  float xv = bf2f(xptr[0]);
  float zv = bf2f(xptr[2048]);
  float4 Bv0 = *(const float4*)(cptr + 64);
  float4 Bv1 = *(const float4*)(cptr + 68);
  float4 Bv2 = *(const float4*)(cptr + 72);
  float4 Bv3 = *(const float4*)(cptr + 76);
  float4 Cv0 = *(const float4*)(cptr + 80);
  float4 Cv1 = *(const float4*)(cptr + 84);
  float4 Cv2 = *(const float4*)(cptr + 88);
  float4 Cv3 = *(const float4*)(cptr + 92);

  for (int t = 0; t < LCH; ++t) {
    const float dtc = dt, xvc = xv, zvc = zv;
    float Bc[NST] = {Bv0.x,Bv0.y,Bv0.z,Bv0.w, Bv1.x,Bv1.y,Bv1.z,Bv1.w,
                     Bv2.x,Bv2.y,Bv2.z,Bv2.w, Bv3.x,Bv3.y,Bv3.z,Bv3.w};
    float Cc[NST] = {Cv0.x,Cv0.y,Cv0.z,Cv0.w, Cv1.x,Cv1.y,Cv1.z,Cv1.w,
                     Cv2.x,Cv2.y,Cv2.z,Cv2.w, Cv3.x,Cv3.y,Cv3.z,Cv3.w};
    if (t + 1 < LCH) {
      const size_t tn = (size_t)(t+1);
      dt = bf2f(dptr[tn*DI]);
      xv = bf2f(xptr[tn*4096]);
      zv = bf2f(xptr[tn*4096 + 2048]);
      const float* cp = cptr + tn*96;
      Bv0 = *(const float4*)(cp + 64);
      Bv1 = *(const float4*)(cp + 68);
      Bv2 = *(const float4*)(cp + 72);
      Bv3 = *(const float4*)(cp + 76);
      Cv0 = *(const float4*)(cp + 80);
      Cv1 = *(const float4*)(cp + 84);
      Cv2 = *(const float4*)(cp + 88);
      Cv3 = *(const float4*)(cp + 92);
    }
    const float xdt = xvc * dtc;
    float y = 0.f;
#pragma unroll
    for (int nn = 0; nn < NST; ++nn) {
      float dA = exp2f(dtc * A2[nn]);
      h[nn] = h[nn]*dA + xdt*Bc[nn];
      y += h[nn]*Cc[nn];
    }
    y += xvc * Dv;
    y *= zvc / (1.f + __expf(-zvc));
    yp[(size_t)t*DI] = f2bf(y);
  }
}

// ---------------------------------------------------------------------------
extern "C" void kernel_launch(void* const* d_in, const int* in_sizes, int n_in,
                              void* d_out, int out_size, void* d_ws, size_t ws_size,
                              hipStream_t stream)
{
  const float* u     = (const float*)d_in[0];
  const float* W_in  = (const float*)d_in[1];
  const float* b_in  = (const float*)d_in[2];
  const float* W_x   = (const float*)d_in[3];
  const float* b_x   = (const float*)d_in[4];
  const float* W_dt  = (const float*)d_in[5];
  const float* b_dt  = (const float*)d_in[6];
  const float* A_log = (const float*)d_in[7];
  const float* Dp    = (const float*)d_in[8];
  const float* W_out = (const float*)d_in[9];
  const float* b_out = (const float*)d_in[10];
  float* out = (float*)d_out;

  // workspace (~90.8 MB total, all chunks 16B-aligned)
  unsigned short* ui_bf    = (unsigned short*)d_ws;             // MT*4096 u16
  float*          dbc      = (float*)(ui_bf + (size_t)MT*4096); // MT*96 f32
  unsigned short* delta_bf = (unsigned short*)(dbc + (size_t)MT*96);   // MT*DI u16
  unsigned short* y_bf     = delta_bf + (size_t)MT*DI;          // MT*DI u16
  unsigned short* wout_bf  = y_bf + (size_t)MT*DI;              // DM*DI u16
  unsigned short* wx_bf    = wout_bf + (size_t)DM*DI;           // 96*DI u16
  unsigned short* wdt_bf   = wx_bf + (size_t)96*DI;             // DI*64 u16
  unsigned short* draw_bf  = wdt_bf + (size_t)DI*64;            // MT*64 u16
  float*          S        = (float*)(draw_bf + (size_t)MT*64); // B*CHK*DI*NST f32

  // d_out doubles as scratch: u_bf+Win_bf (dead after gemm1), then P, then out
  unsigned short* u_bf   = (unsigned short*)d_out;              // MT*DM u16
  unsigned short* win_bf = u_bf + (size_t)MT*DM;                // 2DI*DM u16
  float* P = (float*)d_out;                                     // B*CHK*DI*NST f32

  // 0) fp32 -> bf16 conversions
  conv_bf16_kernel<<<4096, 256, 0, stream>>>(u,     u_bf,    MT*DM/4);
  conv_bf16_kernel<<<4096, 256, 0, stream>>>(W_in,  win_bf,  2*DI*DM/4);
  conv_bf16_kernel<<<2048, 256, 0, stream>>>(W_out, wout_bf, DM*DI/4);
  conv_bf16_kernel<<<192,  256, 0, stream>>>(W_x,   wx_bf,   96*DI/4);
  conv_bf16_kernel<<<128,  256, 0, stream>>>(W_dt,  wdt_bf,  DI*64/4);

  // 1) ui = u @ W_in^T + b_in   (M=4096, N=4096, K=1024) -> bf16
  gemm2_kernel<128, true, 4096, 0><<<32*32, 256, 0, stream>>>(
      u_bf, win_bf, b_in, ui_bf, DM, 32);

  // 2) dbc = x @ W_x^T + b_x    (MFMA; draw cols -> bf16, B/C cols -> fp32)
  dbc_mfma_kernel<<<MT/64, 256, 0, stream>>>(ui_bf, wx_bf, b_x, dbc, draw_bf);

  // 3) delta = softplus(draw @ W_dt^T + b_dt)  (MFMA, M=4096,N=2048,K=64) -> bf16
  gemm2_kernel<128, true, 2048, 1><<<16*32, 256, 0, stream>>>(
      draw_bf, wdt_bf, b_dt, delta_bf, 64, 16);

  // 4) chunk-parallel selective scan (P overwrites u_bf/win_bf — dead now)
  scanA_kernel<<<BATCH*CHK*DI/256, 256, 0, stream>>>(ui_bf, dbc, delta_bf, A_log, P, S);
  scanB_kernel<<<BATCH*DI*4/256, 256, 0, stream>>>(P, S);
  scanC_kernel<<<BATCH*CHK*DI/256, 256, 0, stream>>>(ui_bf, dbc, delta_bf, A_log, Dp, S, y_bf);

  // 5) out = y @ W_out^T + b_out (M=4096, N=1024, K=2048) -> f32, BN=64
  gemm2_kernel<64, false, 1024, 0><<<16*32, 256, 0, stream>>>(
      y_bf, wout_bf, b_out, out, DI, 16);
}

// Round 7
// 215.445 us; speedup vs baseline: 1.2751x; 1.2751x over previous
//
#include <hip/hip_runtime.h>
#include <math.h>

#define BATCH 2
#define SEQ   2048
#define DM    1024
#define DI    2048
#define NST   16
#define MT    (BATCH*SEQ)   // 4096
#define CHK   64            // chunks along T
#define LCH   (SEQ/CHK)     // 32 steps per chunk

typedef __attribute__((ext_vector_type(8))) short  bf16x8;
typedef __attribute__((ext_vector_type(4))) float  f32x4;

static __device__ __forceinline__ unsigned short f2bf(float f) {
  unsigned u = __float_as_uint(f);
  u += 0x7fff + ((u >> 16) & 1);          // RNE
  return (unsigned short)(u >> 16);
}
static __device__ __forceinline__ float bf2f(unsigned short h) {
  return __uint_as_float(((unsigned)h) << 16);
}
// native 2^x — exactly one v_exp_f32 (exp2f without -ffast-math is an OCML call)
static __device__ __forceinline__ float fexp2(float x) {
  float r;
  asm("v_exp_f32 %0, %1" : "=v"(r) : "v"(x));
  return r;
}
// native log2
static __device__ __forceinline__ float flog2(float x) {
  float r;
  asm("v_log_f32 %0, %1" : "=v"(r) : "v"(x));
  return r;
}

// ---------------------------------------------------------------------------
// fp32 -> bf16 bulk convert (float4 in, ushort4 out)
// ---------------------------------------------------------------------------
__global__ __launch_bounds__(256) void conv_bf16_kernel(
    const float* __restrict__ src, unsigned short* __restrict__ dst, int n4)
{
  int i = blockIdx.x * 256 + threadIdx.x;
  if (i < n4) {
    float4 v = ((const float4*)src)[i];
    ushort4 o;
    o.x = f2bf(v.x); o.y = f2bf(v.y); o.z = f2bf(v.z); o.w = f2bf(v.w);
    ((ushort4*)dst)[i] = o;
  }
}

// ---------------------------------------------------------------------------
// A2 table: A2[d*NST+n] = -log2(e) * exp(A_log[d*NST+n])
// ---------------------------------------------------------------------------
__global__ __launch_bounds__(256) void a2tab_kernel(
    const float* __restrict__ A_log, float* __restrict__ A2tab)
{
  int i = blockIdx.x * 256 + threadIdx.x;   // over DI*NST/4
  float4 v = ((const float4*)A_log)[i];
  float4 o;
  o.x = -1.44269504f * __expf(v.x);
  o.y = -1.44269504f * __expf(v.y);
  o.z = -1.44269504f * __expf(v.z);
  o.w = -1.44269504f * __expf(v.w);
  ((float4*)A2tab)[i] = o;
}

// ---------------------------------------------------------------------------
// bf16 MFMA GEMM v2: C(M,N) = act(A(M,K) @ B(N,K)^T + bias(N))
// Tile 128 x BN, BK=64, 256 thr = 4 waves (2x2); double-buffered LDS with
// next-tile prefetch before compute; one barrier per K-tile.
// ACT: 0 = none, 1 = softplus.
// ---------------------------------------------------------------------------
template<int BN, bool OUT_BF16, int LDC, int ACT>
__global__ __launch_bounds__(256, 2) void gemm2_kernel(
    const unsigned short* __restrict__ A,
    const unsigned short* __restrict__ B,
    const float* __restrict__ bias,
    void* __restrict__ Cout, int K, int nbx)
{
  constexpr int NJ = BN / 32;               // N-frags per wave
  __shared__ unsigned short Abuf[2][2][128*32];   // [buf][k-half][row*32+col]
  __shared__ unsigned short Bbuf[2][2][BN*32];

  // XCD-aware block swizzle (grid % 8 == 0)
  const int nwg = gridDim.x;
  const int cpx = nwg >> 3;
  const int bid = blockIdx.x;
  const int swz = (bid & 7) * cpx + (bid >> 3);
  const int bx = swz % nbx;
  const int by = swz / nbx;

  const int tid  = threadIdx.x;
  const int lane = tid & 63;
  const int wid  = tid >> 6;
  const int wr   = wid >> 1;    // wave row (0..1)
  const int wc   = wid & 1;     // wave col (0..1)
  const int lr    = lane >> 2;  // staging: row within 16-row group
  const int lslot = lane & 3;   // staging: 16B slot within 32-elem row

  f32x4 zero = {0.f, 0.f, 0.f, 0.f};
  f32x4 acc[4][NJ];
#pragma unroll
  for (int i = 0; i < 4; ++i)
#pragma unroll
    for (int j = 0; j < NJ; ++j) acc[i][j] = zero;

  const size_t arow0 = (size_t)by * 128;
  const size_t brow0 = (size_t)bx * BN;
  const int NT = K >> 6;        // K-tiles of 64

  auto STAGE = [&](int buf, int k0) {
#pragma unroll
    for (int half = 0; half < 2; ++half) {
#pragma unroll
      for (int i = 0; i < 2; ++i) {         // A: 8 groups of 16 rows
        const int Rb = (wid + i*4) * 16;
        const int r  = Rb + lr;
        const int c8 = lslot ^ ((r >> 1) & 3);
        const unsigned short* ga = A + (arow0 + r)*(size_t)K + k0 + half*32 + c8*8;
        __builtin_amdgcn_global_load_lds(
            (const __attribute__((address_space(1))) void*)ga,
            (__attribute__((address_space(3))) void*)(&Abuf[buf][half][Rb*32]),
            16, 0, 0);
      }
#pragma unroll
      for (int i = 0; i < BN/64; ++i) {     // B: BN/16 groups
        const int Rb = (wid + i*4) * 16;
        const int r  = Rb + lr;
        const int c8 = lslot ^ ((r >> 1) & 3);
        const unsigned short* gb = B + (brow0 + r)*(size_t)K + k0 + half*32 + c8*8;
        __builtin_amdgcn_global_load_lds(
            (const __attribute__((address_space(1))) void*)gb,
            (__attribute__((address_space(3))) void*)(&Bbuf[buf][half][Rb*32]),
            16, 0, 0);
      }
    }
  };

  STAGE(0, 0);
  __syncthreads();

  const int lrow = lane & 15, k8 = lane >> 4;
  int cur = 0;
  for (int kt = 0; kt < NT; ++kt) {
    if (kt + 1 < NT) STAGE(cur ^ 1, (kt + 1) * 64);

#pragma unroll
    for (int half = 0; half < 2; ++half) {
      bf16x8 af[4], bfr[NJ];
#pragma unroll
      for (int mi = 0; mi < 4; ++mi) {
        const int r = wr*64 + mi*16 + lrow;
        af[mi] = *(const bf16x8*)&Abuf[cur][half][r*32 + (k8 ^ ((r >> 1) & 3))*8];
      }
#pragma unroll
      for (int nj = 0; nj < NJ; ++nj) {
        const int r = wc*(BN/2) + nj*16 + lrow;
        bfr[nj] = *(const bf16x8*)&Bbuf[cur][half][r*32 + (k8 ^ ((r >> 1) & 3))*8];
      }
      __builtin_amdgcn_s_setprio(1);
#pragma unroll
      for (int mi = 0; mi < 4; ++mi)
#pragma unroll
        for (int nj = 0; nj < NJ; ++nj)
          acc[mi][nj] = __builtin_amdgcn_mfma_f32_16x16x32_bf16(
                            af[mi], bfr[nj], acc[mi][nj], 0, 0, 0);
      __builtin_amdgcn_s_setprio(0);
    }
    __syncthreads();
    cur ^= 1;
  }

  const int lcol = lane & 15, lrq = lane >> 4;
#pragma unroll
  for (int nj = 0; nj < NJ; ++nj) {
    const int colg = bx*BN + wc*(BN/2) + nj*16 + lcol;
    const float bv = bias[colg];
#pragma unroll
    for (int mi = 0; mi < 4; ++mi) {
      const int rowg = by*128 + wr*64 + mi*16 + lrq*4;
#pragma unroll
      for (int q = 0; q < 4; ++q) {
        float v = acc[mi][nj][q] + bv;
        if constexpr (ACT == 1) {
          // softplus(v) = max(v,0) + log(1 + exp(-|v|)), native exp2/log2
          float e = fexp2(-1.44269504f * fabsf(v));
          v = fmaxf(v, 0.f) + 0.69314718f * flog2(1.f + e);
        }
        if constexpr (OUT_BF16)
          ((unsigned short*)Cout)[(size_t)(rowg + q)*LDC + colg] = f2bf(v);
        else
          ((float*)Cout)[(size_t)(rowg + q)*LDC + colg] = v;
      }
    }
  }
}

// ---------------------------------------------------------------------------
// dbc = x @ W_x^T + b_x via MFMA.  Cols 0..63 (delta_raw) -> draw_bf (bf16),
// cols 64..95 (B,C) -> dbc fp32.
// ---------------------------------------------------------------------------
__global__ __launch_bounds__(256) void dbc_mfma_kernel(
    const unsigned short* __restrict__ A,     // ui_bf
    const unsigned short* __restrict__ Bw,    // wx_bf
    const float* __restrict__ bx,
    float* __restrict__ dbc,
    unsigned short* __restrict__ draw_bf)
{
  __shared__ unsigned short Abuf[64*32];   // 4 KiB
  __shared__ unsigned short Bbuf[96*32];   // 6 KiB

  const int tid  = threadIdx.x;
  const int lane = tid & 63;
  const int wid  = tid >> 6;
  const int lr    = lane >> 2;
  const int lslot = lane & 3;
  const size_t arow0 = (size_t)blockIdx.x * 64;

  f32x4 zero = {0.f, 0.f, 0.f, 0.f};
  f32x4 acc[6];
#pragma unroll
  for (int j = 0; j < 6; ++j) acc[j] = zero;

  for (int k0 = 0; k0 < DI; k0 += 32) {
    {
      const int Rb = wid*16;
      const int r  = Rb + lr;
      const int c8 = lslot ^ ((r >> 1) & 3);
      const unsigned short* ga = A + (arow0 + r)*4096 + k0 + c8*8;
      __builtin_amdgcn_global_load_lds(
          (const __attribute__((address_space(1))) void*)ga,
          (__attribute__((address_space(3))) void*)(Abuf + Rb*32), 16, 0, 0);
    }
    if (wid < 3) {
#pragma unroll
      for (int i = 0; i < 2; ++i) {
        const int Rb = wid*32 + i*16;
        const int r  = Rb + lr;
        const int c8 = lslot ^ ((r >> 1) & 3);
        const unsigned short* gb = Bw + (size_t)r*DI + k0 + c8*8;
        __builtin_amdgcn_global_load_lds(
            (const __attribute__((address_space(1))) void*)gb,
            (__attribute__((address_space(3))) void*)(Bbuf + Rb*32), 16, 0, 0);
      }
    }
    __syncthreads();

    const int lrow = lane & 15, k8 = lane >> 4;
    const int ra = wid*16 + lrow;
    bf16x8 af = *(const bf16x8*)&Abuf[ra*32 + (k8 ^ ((ra >> 1) & 3))*8];
#pragma unroll
    for (int nj = 0; nj < 6; ++nj) {
      const int rb = nj*16 + lrow;
      bf16x8 bf_ = *(const bf16x8*)&Bbuf[rb*32 + (k8 ^ ((rb >> 1) & 3))*8];
      acc[nj] = __builtin_amdgcn_mfma_f32_16x16x32_bf16(af, bf_, acc[nj], 0, 0, 0);
    }
    __syncthreads();
  }

  const int lcol = lane & 15, lrq = lane >> 4;
  const int rowg = (int)arow0 + wid*16 + lrq*4;
#pragma unroll
  for (int nj = 0; nj < 6; ++nj) {
    const int colg = nj*16 + lcol;
    const float bv = bx[colg];
#pragma unroll
    for (int q = 0; q < 4; ++q) {
      float v = acc[nj][q] + bv;
      if (nj < 4)
        draw_bf[(size_t)(rowg + q)*64 + colg] = f2bf(v);
      else
        dbc[(size_t)(rowg + q)*96 + colg] = v;
    }
  }
}

// ---------------------------------------------------------------------------
// Chunked scan, pass A: local scan from h=0; emits P = exp(A*sum dt), S = h_end
// grid = BATCH*CHK*DI/256 = 2048; (b,c) from blockIdx -> uniform dbc rows ->
// scalar loads.  A2 from precomputed table.
// ---------------------------------------------------------------------------
__global__ __launch_bounds__(256) void scanA_kernel(
    const unsigned short* __restrict__ uib,
    const float* __restrict__ dbc,
    const unsigned short* __restrict__ delta_bf,
    const float* __restrict__ A2tab,
    float* __restrict__ P,
    float* __restrict__ S)
{
  const int bid = blockIdx.x;
  const int d   = (bid & 7)*256 + threadIdx.x;
  const int c   = (bid >> 3) & (CHK-1);
  const int b   = bid >> 9;

  float A2[NST];
  {
    const float4* ap = (const float4*)(A2tab + (size_t)d*NST);
#pragma unroll
    for (int q = 0; q < 4; ++q) {
      float4 v = ap[q];
      A2[q*4+0] = v.x; A2[q*4+1] = v.y; A2[q*4+2] = v.z; A2[q*4+3] = v.w;
    }
  }

  float h[NST];
#pragma unroll
  for (int nn = 0; nn < NST; ++nn) h[nn] = 0.f;
  float sdt = 0.f;

  const int t0 = c * LCH;
  const unsigned short* dptr = delta_bf + ((size_t)b*SEQ + t0)*DI + d;
  const unsigned short* xptr = uib      + ((size_t)b*SEQ + t0)*4096 + d;
  const float* bptr          = dbc      + ((size_t)b*SEQ + t0)*96 + 64;

  float dt = bf2f(dptr[0]);
  float xv = bf2f(xptr[0]);
  float4 Bv0 = *(const float4*)(bptr + 0);
  float4 Bv1 = *(const float4*)(bptr + 4);
  float4 Bv2 = *(const float4*)(bptr + 8);
  float4 Bv3 = *(const float4*)(bptr + 12);

  for (int t = 0; t < LCH; ++t) {
    const float dtc = dt, xvc = xv;
    float Bc[NST] = {Bv0.x,Bv0.y,Bv0.z,Bv0.w, Bv1.x,Bv1.y,Bv1.z,Bv1.w,
                     Bv2.x,Bv2.y,Bv2.z,Bv2.w, Bv3.x,Bv3.y,Bv3.z,Bv3.w};
    if (t + 1 < LCH) {
      const size_t tn = (size_t)(t+1);
      dt = bf2f(dptr[tn*DI]);
      xv = bf2f(xptr[tn*4096]);
      const float* bp = bptr + tn*96;
      Bv0 = *(const float4*)(bp + 0);
      Bv1 = *(const float4*)(bp + 4);
      Bv2 = *(const float4*)(bp + 8);
      Bv3 = *(const float4*)(bp + 12);
    }
    sdt += dtc;
    const float xdt = xvc * dtc;
#pragma unroll
    for (int nn = 0; nn < NST; ++nn) {
      float dA = fexp2(dtc * A2[nn]);
      h[nn] = h[nn]*dA + xdt*Bc[nn];
    }
  }

  float* Pp = P + (((size_t)b*CHK + c)*DI + d)*NST;
  float* Sp = S + (((size_t)b*CHK + c)*DI + d)*NST;
#pragma unroll
  for (int q = 0; q < 4; ++q) {
    float4 pv = { fexp2(A2[q*4+0]*sdt), fexp2(A2[q*4+1]*sdt),
                  fexp2(A2[q*4+2]*sdt), fexp2(A2[q*4+3]*sdt) };
    float4 sv = { h[q*4+0], h[q*4+1], h[q*4+2], h[q*4+3] };
    *(float4*)(Pp + q*4) = pv;
    *(float4*)(Sp + q*4) = sv;
  }
}

// ---------------------------------------------------------------------------
// Chunked scan, pass B: inter-chunk scan; S replaced by carry-in state.
// ---------------------------------------------------------------------------
__global__ __launch_bounds__(256) void scanB_kernel(
    const float* __restrict__ P, float* __restrict__ S)
{
  const int gid = blockIdx.x*256 + threadIdx.x;
  const int n4 = gid & 3;
  const int d  = (gid >> 2) & (DI-1);
  const int b  = gid >> 13;

  float4 h = {0.f, 0.f, 0.f, 0.f};
  for (int c = 0; c < CHK; ++c) {
    const size_t idx = (((size_t)b*CHK + c)*DI + d)*NST + n4*4;
    float4 p = *(const float4*)(P + idx);
    float4 s = *(const float4*)(S + idx);
    *(float4*)(S + idx) = h;
    h.x = h.x*p.x + s.x;
    h.y = h.y*p.y + s.y;
    h.z = h.z*p.z + s.z;
    h.w = h.w*p.w + s.w;
  }
}

// ---------------------------------------------------------------------------
// Chunked scan, pass C: seeded local scan; y + skip + SiLU gate -> y_bf (bf16)
// ---------------------------------------------------------------------------
__global__ __launch_bounds__(256) void scanC_kernel(
    const unsigned short* __restrict__ uib,
    const float* __restrict__ dbc,
    const unsigned short* __restrict__ delta_bf,
    const float* __restrict__ A2tab,
    const float* __restrict__ Dp,
    const float* __restrict__ S,
    unsigned short* __restrict__ y_bf)
{
  const int bid = blockIdx.x;
  const int d   = (bid & 7)*256 + threadIdx.x;
  const int c   = (bid >> 3) & (CHK-1);
  const int b   = bid >> 9;

  float A2[NST];
  {
    const float4* ap = (const float4*)(A2tab + (size_t)d*NST);
#pragma unroll
    for (int q = 0; q < 4; ++q) {
      float4 v = ap[q];
      A2[q*4+0] = v.x; A2[q*4+1] = v.y; A2[q*4+2] = v.z; A2[q*4+3] = v.w;
    }
  }
  const float Dv = Dp[d];

  float h[NST];
  {
    const float* Sp = S + (((size_t)b*CHK + c)*DI + d)*NST;
#pragma unroll
    for (int q = 0; q < 4; ++q) {
      float4 sv = *(const float4*)(Sp + q*4);
      h[q*4+0] = sv.x; h[q*4+1] = sv.y; h[q*4+2] = sv.z; h[q*4+3] = sv.w;
    }
  }

  const int t0 = c * LCH;
  const unsigned short* dptr = delta_bf + ((size_t)b*SEQ + t0)*DI + d;
  const unsigned short* xptr = uib      + ((size_t)b*SEQ + t0)*4096 + d;
  const float* cptr          = dbc      + ((size_t)b*SEQ + t0)*96;
  unsigned short* yp         = y_bf     + ((size_t)b*SEQ + t0)*DI + d;

  float dt = bf2f(dptr[0]);
  float xv = bf2f(xptr[0]);
  float zv = bf2f(xptr[2048]);
  float4 Bv0 = *(const float4*)(cptr + 64);
  float4 Bv1 = *(const float4*)(cptr + 68);
  float4 Bv2 = *(const float4*)(cptr + 72);
  float4 Bv3 = *(const float4*)(cptr + 76);
  float4 Cv0 = *(const float4*)(cptr + 80);
  float4 Cv1 = *(const float4*)(cptr + 84);
  float4 Cv2 = *(const float4*)(cptr + 88);
  float4 Cv3 = *(const float4*)(cptr + 92);

  for (int t = 0; t < LCH; ++t) {
    const float dtc = dt, xvc = xv, zvc = zv;
    float Bc[NST] = {Bv0.x,Bv0.y,Bv0.z,Bv0.w, Bv1.x,Bv1.y,Bv1.z,Bv1.w,
                     Bv2.x,Bv2.y,Bv2.z,Bv2.w, Bv3.x,Bv3.y,Bv3.z,Bv3.w};
    float Cc[NST] = {Cv0.x,Cv0.y,Cv0.z,Cv0.w, Cv1.x,Cv1.y,Cv1.z,Cv1.w,
                     Cv2.x,Cv2.y,Cv2.z,Cv2.w, Cv3.x,Cv3.y,Cv3.z,Cv3.w};
    if (t + 1 < LCH) {
      const size_t tn = (size_t)(t+1);
      dt = bf2f(dptr[tn*DI]);
      xv = bf2f(xptr[tn*4096]);
      zv = bf2f(xptr[tn*4096 + 2048]);
      const float* cp = cptr + tn*96;
      Bv0 = *(const float4*)(cp + 64);
      Bv1 = *(const float4*)(cp + 68);
      Bv2 = *(const float4*)(cp + 72);
      Bv3 = *(const float4*)(cp + 76);
      Cv0 = *(const float4*)(cp + 80);
      Cv1 = *(const float4*)(cp + 84);
      Cv2 = *(const float4*)(cp + 88);
      Cv3 = *(const float4*)(cp + 92);
    }
    const float xdt = xvc * dtc;
    float y = 0.f;
#pragma unroll
    for (int nn = 0; nn < NST; ++nn) {
      float dA = fexp2(dtc * A2[nn]);
      h[nn] = h[nn]*dA + xdt*Bc[nn];
      y += h[nn]*Cc[nn];
    }
    y += xvc * Dv;
    // SiLU gate: z * sigmoid(z) = z / (1 + exp(-z)), native exp2
    y *= zvc / (1.f + fexp2(-1.44269504f * zvc));
    yp[(size_t)t*DI] = f2bf(y);
  }
}

// ---------------------------------------------------------------------------
extern "C" void kernel_launch(void* const* d_in, const int* in_sizes, int n_in,
                              void* d_out, int out_size, void* d_ws, size_t ws_size,
                              hipStream_t stream)
{
  const float* u     = (const float*)d_in[0];
  const float* W_in  = (const float*)d_in[1];
  const float* b_in  = (const float*)d_in[2];
  const float* W_x   = (const float*)d_in[3];
  const float* b_x   = (const float*)d_in[4];
  const float* W_dt  = (const float*)d_in[5];
  const float* b_dt  = (const float*)d_in[6];
  const float* A_log = (const float*)d_in[7];
  const float* Dp    = (const float*)d_in[8];
  const float* W_out = (const float*)d_in[9];
  const float* b_out = (const float*)d_in[10];
  float* out = (float*)d_out;

  // workspace (~91 MB total, all chunks 16B-aligned)
  unsigned short* ui_bf    = (unsigned short*)d_ws;             // MT*4096 u16
  float*          dbc      = (float*)(ui_bf + (size_t)MT*4096); // MT*96 f32
  unsigned short* delta_bf = (unsigned short*)(dbc + (size_t)MT*96);   // MT*DI u16
  unsigned short* y_bf     = delta_bf + (size_t)MT*DI;          // MT*DI u16
  unsigned short* wout_bf  = y_bf + (size_t)MT*DI;              // DM*DI u16
  unsigned short* wx_bf    = wout_bf + (size_t)DM*DI;           // 96*DI u16
  unsigned short* wdt_bf   = wx_bf + (size_t)96*DI;             // DI*64 u16
  unsigned short* draw_bf  = wdt_bf + (size_t)DI*64;            // MT*64 u16
  float*          S        = (float*)(draw_bf + (size_t)MT*64); // B*CHK*DI*NST f32
  float*          A2tab    = S + (size_t)BATCH*CHK*DI*NST;      // DI*NST f32

  // d_out doubles as scratch: u_bf+Win_bf (dead after gemm1), then P, then out
  unsigned short* u_bf   = (unsigned short*)d_out;              // MT*DM u16
  unsigned short* win_bf = u_bf + (size_t)MT*DM;                // 2DI*DM u16
  float* P = (float*)d_out;                                     // B*CHK*DI*NST f32

  // 0) fp32 -> bf16 conversions + A2 table
  conv_bf16_kernel<<<4096, 256, 0, stream>>>(u,     u_bf,    MT*DM/4);
  conv_bf16_kernel<<<4096, 256, 0, stream>>>(W_in,  win_bf,  2*DI*DM/4);
  conv_bf16_kernel<<<2048, 256, 0, stream>>>(W_out, wout_bf, DM*DI/4);
  conv_bf16_kernel<<<192,  256, 0, stream>>>(W_x,   wx_bf,   96*DI/4);
  conv_bf16_kernel<<<128,  256, 0, stream>>>(W_dt,  wdt_bf,  DI*64/4);
  a2tab_kernel<<<DI*NST/1024, 256, 0, stream>>>(A_log, A2tab);

  // 1) ui = u @ W_in^T + b_in   (M=4096, N=4096, K=1024) -> bf16
  gemm2_kernel<128, true, 4096, 0><<<32*32, 256, 0, stream>>>(
      u_bf, win_bf, b_in, ui_bf, DM, 32);

  // 2) dbc = x @ W_x^T + b_x    (MFMA; draw cols -> bf16, B/C cols -> fp32)
  dbc_mfma_kernel<<<MT/64, 256, 0, stream>>>(ui_bf, wx_bf, b_x, dbc, draw_bf);

  // 3) delta = softplus(draw @ W_dt^T + b_dt)  (MFMA, M=4096,N=2048,K=64) -> bf16
  gemm2_kernel<128, true, 2048, 1><<<16*32, 256, 0, stream>>>(
      draw_bf, wdt_bf, b_dt, delta_bf, 64, 16);

  // 4) chunk-parallel selective scan (P overwrites u_bf/win_bf — dead now)
  scanA_kernel<<<BATCH*CHK*DI/256, 256, 0, stream>>>(ui_bf, dbc, delta_bf, A2tab, P, S);
  scanB_kernel<<<BATCH*DI*4/256, 256, 0, stream>>>(P, S);
  scanC_kernel<<<BATCH*CHK*DI/256, 256, 0, stream>>>(ui_bf, dbc, delta_bf, A2tab, Dp, S, y_bf);

  // 5) out = y @ W_out^T + b_out (M=4096, N=1024, K=2048) -> f32, BN=64
  gemm2_kernel<64, false, 1024, 0><<<16*32, 256, 0, stream>>>(
      y_bf, wout_bf, b_out, out, DI, 16);
}

// Round 8
// 185.218 us; speedup vs baseline: 1.4832x; 1.1632x over previous
//
#include <hip/hip_runtime.h>
#include <math.h>

#define BATCH 2
#define SEQ   2048
#define DM    1024
#define DI    2048
#define NST   16
#define MT    (BATCH*SEQ)   // 4096
#define CHK   64            // chunks along T
#define LCH   (SEQ/CHK)     // 32 steps per chunk

typedef __attribute__((ext_vector_type(8))) short  bf16x8;
typedef __attribute__((ext_vector_type(4))) float  f32x4;

static __device__ __forceinline__ unsigned short f2bf(float f) {
  unsigned u = __float_as_uint(f);
  u += 0x7fff + ((u >> 16) & 1);          // RNE
  return (unsigned short)(u >> 16);
}
static __device__ __forceinline__ float bf2f(unsigned short h) {
  return __uint_as_float(((unsigned)h) << 16);
}
// native 2^x — exactly one v_exp_f32
static __device__ __forceinline__ float fexp2(float x) {
  float r;
  asm("v_exp_f32 %0, %1" : "=v"(r) : "v"(x));
  return r;
}
// native log2
static __device__ __forceinline__ float flog2(float x) {
  float r;
  asm("v_log_f32 %0, %1" : "=v"(r) : "v"(x));
  return r;
}

// ---------------------------------------------------------------------------
// Fused fp32->bf16 conversions for all weights/inputs + A2 table, one launch.
// Segment sizes in float4 units (compile-time).
// ---------------------------------------------------------------------------
#define SEG_U    (MT*DM/4)        // 1048576
#define SEG_WIN  (2*DI*DM/4)      // 1048576
#define SEG_WOUT (DM*DI/4)        // 524288
#define SEG_WX   (96*DI/4)        // 49152
#define SEG_WDT  (DI*64/4)        // 32768
#define SEG_A    (DI*NST/4)       // 8192
#define CUM0 SEG_U
#define CUM1 (CUM0+SEG_WIN)
#define CUM2 (CUM1+SEG_WOUT)
#define CUM3 (CUM2+SEG_WX)
#define CUM4 (CUM3+SEG_WDT)
#define CUM5 (CUM4+SEG_A)         // 2711552 total float4s

__global__ __launch_bounds__(256) void convall_kernel(
    const float* __restrict__ u, const float* __restrict__ W_in,
    const float* __restrict__ W_out, const float* __restrict__ W_x,
    const float* __restrict__ W_dt, const float* __restrict__ A_log,
    unsigned short* __restrict__ u_bf, unsigned short* __restrict__ win_bf,
    unsigned short* __restrict__ wout_bf, unsigned short* __restrict__ wx_bf,
    unsigned short* __restrict__ wdt_bf, float* __restrict__ A2tab)
{
  const int gid = blockIdx.x*256 + threadIdx.x;
  const float4* src; ushort4* dst; int idx;
  if (gid < CUM0)      { idx = gid;        src = (const float4*)u;     dst = (ushort4*)u_bf; }
  else if (gid < CUM1) { idx = gid - CUM0; src = (const float4*)W_in;  dst = (ushort4*)win_bf; }
  else if (gid < CUM2) { idx = gid - CUM1; src = (const float4*)W_out; dst = (ushort4*)wout_bf; }
  else if (gid < CUM3) { idx = gid - CUM2; src = (const float4*)W_x;   dst = (ushort4*)wx_bf; }
  else if (gid < CUM4) { idx = gid - CUM3; src = (const float4*)W_dt;  dst = (ushort4*)wdt_bf; }
  else if (gid < CUM5) {
    int i = gid - CUM4;
    float4 v = ((const float4*)A_log)[i];
    float4 o;
    o.x = -1.44269504f * __expf(v.x);
    o.y = -1.44269504f * __expf(v.y);
    o.z = -1.44269504f * __expf(v.z);
    o.w = -1.44269504f * __expf(v.w);
    ((float4*)A2tab)[i] = o;
    return;
  } else return;
  float4 v = src[idx];
  ushort4 o;
  o.x = f2bf(v.x); o.y = f2bf(v.y); o.z = f2bf(v.z); o.w = f2bf(v.w);
  dst[idx] = o;
}

// ---------------------------------------------------------------------------
// bf16 MFMA GEMM v3: C(M,N) = act(A(M,K) @ B(N,K)^T + bias(N))
// Tile 128 x BN, BK = 32 or 64 (NH = BK/32 sub-tiles), 256 thr = 4 waves
// (2x2); double-buffered LDS, next-tile prefetch before compute, one barrier
// per K-tile.  BK=32 keeps LDS at 32 KiB -> ~4 blocks/CU.
// ACT: 0 = none, 1 = softplus.
// ---------------------------------------------------------------------------
template<int BN, int BK, bool OUT_BF16, int LDC, int ACT>
__global__ __launch_bounds__(256, 4) void gemm2_kernel(
    const unsigned short* __restrict__ A,
    const unsigned short* __restrict__ B,
    const float* __restrict__ bias,
    void* __restrict__ Cout, int K, int nbx)
{
  constexpr int NH = BK / 32;               // 32-wide K sub-tiles
  constexpr int NJ = BN / 32;               // N-frags per wave
  __shared__ unsigned short Abuf[2][NH][128*32];
  __shared__ unsigned short Bbuf[2][NH][BN*32];

  // XCD-aware block swizzle (grid % 8 == 0)
  const int nwg = gridDim.x;
  const int cpx = nwg >> 3;
  const int bid = blockIdx.x;
  const int swz = (bid & 7) * cpx + (bid >> 3);
  const int bx = swz % nbx;
  const int by = swz / nbx;

  const int tid  = threadIdx.x;
  const int lane = tid & 63;
  const int wid  = tid >> 6;
  const int wr   = wid >> 1;    // wave row (0..1)
  const int wc   = wid & 1;     // wave col (0..1)
  const int lr    = lane >> 2;  // staging: row within 16-row group
  const int lslot = lane & 3;   // staging: 16B slot within 32-elem row

  f32x4 zero = {0.f, 0.f, 0.f, 0.f};
  f32x4 acc[4][NJ];
#pragma unroll
  for (int i = 0; i < 4; ++i)
#pragma unroll
    for (int j = 0; j < NJ; ++j) acc[i][j] = zero;

  const size_t arow0 = (size_t)by * 128;
  const size_t brow0 = (size_t)bx * BN;
  const int NT = K / BK;

  auto STAGE = [&](int buf, int k0) {
#pragma unroll
    for (int half = 0; half < NH; ++half) {
#pragma unroll
      for (int i = 0; i < 2; ++i) {         // A: 8 groups of 16 rows
        const int Rb = (wid + i*4) * 16;
        const int r  = Rb + lr;
        const int c8 = lslot ^ ((r >> 1) & 3);
        const unsigned short* ga = A + (arow0 + r)*(size_t)K + k0 + half*32 + c8*8;
        __builtin_amdgcn_global_load_lds(
            (const __attribute__((address_space(1))) void*)ga,
            (__attribute__((address_space(3))) void*)(&Abuf[buf][half][Rb*32]),
            16, 0, 0);
      }
#pragma unroll
      for (int i = 0; i < BN/64; ++i) {     // B: BN/16 groups
        const int Rb = (wid + i*4) * 16;
        const int r  = Rb + lr;
        const int c8 = lslot ^ ((r >> 1) & 3);
        const unsigned short* gb = B + (brow0 + r)*(size_t)K + k0 + half*32 + c8*8;
        __builtin_amdgcn_global_load_lds(
            (const __attribute__((address_space(1))) void*)gb,
            (__attribute__((address_space(3))) void*)(&Bbuf[buf][half][Rb*32]),
            16, 0, 0);
      }
    }
  };

  STAGE(0, 0);
  __syncthreads();

  const int lrow = lane & 15, k8 = lane >> 4;
  int cur = 0;
  for (int kt = 0; kt < NT; ++kt) {
    if (kt + 1 < NT) STAGE(cur ^ 1, (kt + 1) * BK);

#pragma unroll
    for (int half = 0; half < NH; ++half) {
      bf16x8 af[4], bfr[NJ];
#pragma unroll
      for (int mi = 0; mi < 4; ++mi) {
        const int r = wr*64 + mi*16 + lrow;
        af[mi] = *(const bf16x8*)&Abuf[cur][half][r*32 + (k8 ^ ((r >> 1) & 3))*8];
      }
#pragma unroll
      for (int nj = 0; nj < NJ; ++nj) {
        const int r = wc*(BN/2) + nj*16 + lrow;
        bfr[nj] = *(const bf16x8*)&Bbuf[cur][half][r*32 + (k8 ^ ((r >> 1) & 3))*8];
      }
      __builtin_amdgcn_s_setprio(1);
#pragma unroll
      for (int mi = 0; mi < 4; ++mi)
#pragma unroll
        for (int nj = 0; nj < NJ; ++nj)
          acc[mi][nj] = __builtin_amdgcn_mfma_f32_16x16x32_bf16(
                            af[mi], bfr[nj], acc[mi][nj], 0, 0, 0);
      __builtin_amdgcn_s_setprio(0);
    }
    __syncthreads();
    cur ^= 1;
  }

  const int lcol = lane & 15, lrq = lane >> 4;
#pragma unroll
  for (int nj = 0; nj < NJ; ++nj) {
    const int colg = bx*BN + wc*(BN/2) + nj*16 + lcol;
    const float bv = bias[colg];
#pragma unroll
    for (int mi = 0; mi < 4; ++mi) {
      const int rowg = by*128 + wr*64 + mi*16 + lrq*4;
#pragma unroll
      for (int q = 0; q < 4; ++q) {
        float v = acc[mi][nj][q] + bv;
        if constexpr (ACT == 1) {
          // softplus(v) = max(v,0) + log(1 + exp(-|v|)), native exp2/log2
          float e = fexp2(-1.44269504f * fabsf(v));
          v = fmaxf(v, 0.f) + 0.69314718f * flog2(1.f + e);
        }
        if constexpr (OUT_BF16)
          ((unsigned short*)Cout)[(size_t)(rowg + q)*LDC + colg] = f2bf(v);
        else
          ((float*)Cout)[(size_t)(rowg + q)*LDC + colg] = v;
      }
    }
  }
}

// ---------------------------------------------------------------------------
// dbc partials: x @ W_x^T, K split 4 ways. grid (MT/64, 4).
// Block (mx, ks): rows mx*64..+64, K in [ks*512, ks*512+512).
// partial[ks][m][96] fp32 (no bias).
// ---------------------------------------------------------------------------
__global__ __launch_bounds__(256) void dbc_mfma_kernel(
    const unsigned short* __restrict__ A,     // ui_bf
    const unsigned short* __restrict__ Bw,    // wx_bf
    float* __restrict__ partial)
{
  __shared__ unsigned short Abuf[64*32];   // 4 KiB
  __shared__ unsigned short Bbuf[96*32];   // 6 KiB

  const int tid  = threadIdx.x;
  const int lane = tid & 63;
  const int wid  = tid >> 6;
  const int lr    = lane >> 2;
  const int lslot = lane & 3;
  const size_t arow0 = (size_t)blockIdx.x * 64;
  const int ks   = blockIdx.y;
  const int k0b  = ks * (DI/4);            // 512-wide K slice

  f32x4 zero = {0.f, 0.f, 0.f, 0.f};
  f32x4 acc[6];
#pragma unroll
  for (int j = 0; j < 6; ++j) acc[j] = zero;

  for (int k0 = k0b; k0 < k0b + DI/4; k0 += 32) {
    {
      const int Rb = wid*16;
      const int r  = Rb + lr;
      const int c8 = lslot ^ ((r >> 1) & 3);
      const unsigned short* ga = A + (arow0 + r)*4096 + k0 + c8*8;
      __builtin_amdgcn_global_load_lds(
          (const __attribute__((address_space(1))) void*)ga,
          (__attribute__((address_space(3))) void*)(Abuf + Rb*32), 16, 0, 0);
    }
    if (wid < 3) {
#pragma unroll
      for (int i = 0; i < 2; ++i) {
        const int Rb = wid*32 + i*16;
        const int r  = Rb + lr;
        const int c8 = lslot ^ ((r >> 1) & 3);
        const unsigned short* gb = Bw + (size_t)r*DI + k0 + c8*8;
        __builtin_amdgcn_global_load_lds(
            (const __attribute__((address_space(1))) void*)gb,
            (__attribute__((address_space(3))) void*)(Bbuf + Rb*32), 16, 0, 0);
      }
    }
    __syncthreads();

    const int lrow = lane & 15, k8 = lane >> 4;
    const int ra = wid*16 + lrow;
    bf16x8 af = *(const bf16x8*)&Abuf[ra*32 + (k8 ^ ((ra >> 1) & 3))*8];
#pragma unroll
    for (int nj = 0; nj < 6; ++nj) {
      const int rb = nj*16 + lrow;
      bf16x8 bf_ = *(const bf16x8*)&Bbuf[rb*32 + (k8 ^ ((rb >> 1) & 3))*8];
      acc[nj] = __builtin_amdgcn_mfma_f32_16x16x32_bf16(af, bf_, acc[nj], 0, 0, 0);
    }
    __syncthreads();
  }

  const int lcol = lane & 15, lrq = lane >> 4;
  const int rowg = (int)arow0 + wid*16 + lrq*4;
#pragma unroll
  for (int nj = 0; nj < 6; ++nj) {
    const int colg = nj*16 + lcol;
#pragma unroll
    for (int q = 0; q < 4; ++q)
      partial[((size_t)ks*MT + rowg + q)*96 + colg] = acc[nj][q];
  }
}

// ---------------------------------------------------------------------------
// dbc reduce: sum 4 partials + bias; cols 0..63 -> draw_bf, 64..95 -> dbc f32.
// grid = MT*96/256 = 1536.
// ---------------------------------------------------------------------------
__global__ __launch_bounds__(256) void dbc_reduce_kernel(
    const float* __restrict__ partial, const float* __restrict__ bx,
    float* __restrict__ dbc, unsigned short* __restrict__ draw_bf)
{
  const int gid = blockIdx.x*256 + threadIdx.x;   // 0 .. MT*96-1
  const int m = gid / 96;
  const int c = gid - m*96;
  const size_t stride = (size_t)MT*96;
  float s = partial[gid] + partial[gid + stride]
          + partial[gid + 2*stride] + partial[gid + 3*stride] + bx[c];
  if (c < 64) draw_bf[(size_t)m*64 + c] = f2bf(s);
  else        dbc[(size_t)m*96 + c] = s;
}

// ---------------------------------------------------------------------------
// Chunked scan, pass A: local scan from h=0; emits P = exp(A*sum dt), S = h_end
// ---------------------------------------------------------------------------
__global__ __launch_bounds__(256) void scanA_kernel(
    const unsigned short* __restrict__ uib,
    const float* __restrict__ dbc,
    const unsigned short* __restrict__ delta_bf,
    const float* __restrict__ A2tab,
    float* __restrict__ P,
    float* __restrict__ S)
{
  const int bid = blockIdx.x;
  const int d   = (bid & 7)*256 + threadIdx.x;
  const int c   = (bid >> 3) & (CHK-1);
  const int b   = bid >> 9;

  float A2[NST];
  {
    const float4* ap = (const float4*)(A2tab + (size_t)d*NST);
#pragma unroll
    for (int q = 0; q < 4; ++q) {
      float4 v = ap[q];
      A2[q*4+0] = v.x; A2[q*4+1] = v.y; A2[q*4+2] = v.z; A2[q*4+3] = v.w;
    }
  }

  float h[NST];
#pragma unroll
  for (int nn = 0; nn < NST; ++nn) h[nn] = 0.f;
  float sdt = 0.f;

  const int t0 = c * LCH;
  const unsigned short* dptr = delta_bf + ((size_t)b*SEQ + t0)*DI + d;
  const unsigned short* xptr = uib      + ((size_t)b*SEQ + t0)*4096 + d;
  const float* bptr          = dbc      + ((size_t)b*SEQ + t0)*96 + 64;

  float dt = bf2f(dptr[0]);
  float xv = bf2f(xptr[0]);
  float4 Bv0 = *(const float4*)(bptr + 0);
  float4 Bv1 = *(const float4*)(bptr + 4);
  float4 Bv2 = *(const float4*)(bptr + 8);
  float4 Bv3 = *(const float4*)(bptr + 12);

  for (int t = 0; t < LCH; ++t) {
    const float dtc = dt, xvc = xv;
    float Bc[NST] = {Bv0.x,Bv0.y,Bv0.z,Bv0.w, Bv1.x,Bv1.y,Bv1.z,Bv1.w,
                     Bv2.x,Bv2.y,Bv2.z,Bv2.w, Bv3.x,Bv3.y,Bv3.z,Bv3.w};
    if (t + 1 < LCH) {
      const size_t tn = (size_t)(t+1);
      dt = bf2f(dptr[tn*DI]);
      xv = bf2f(xptr[tn*4096]);
      const float* bp = bptr + tn*96;
      Bv0 = *(const float4*)(bp + 0);
      Bv1 = *(const float4*)(bp + 4);
      Bv2 = *(const float4*)(bp + 8);
      Bv3 = *(const float4*)(bp + 12);
    }
    sdt += dtc;
    const float xdt = xvc * dtc;
#pragma unroll
    for (int nn = 0; nn < NST; ++nn) {
      float dA = fexp2(dtc * A2[nn]);
      h[nn] = h[nn]*dA + xdt*Bc[nn];
    }
  }

  float* Pp = P + (((size_t)b*CHK + c)*DI + d)*NST;
  float* Sp = S + (((size_t)b*CHK + c)*DI + d)*NST;
#pragma unroll
  for (int q = 0; q < 4; ++q) {
    float4 pv = { fexp2(A2[q*4+0]*sdt), fexp2(A2[q*4+1]*sdt),
                  fexp2(A2[q*4+2]*sdt), fexp2(A2[q*4+3]*sdt) };
    float4 sv = { h[q*4+0], h[q*4+1], h[q*4+2], h[q*4+3] };
    *(float4*)(Pp + q*4) = pv;
    *(float4*)(Sp + q*4) = sv;
  }
}

// ---------------------------------------------------------------------------
// Chunked scan, pass B: inter-chunk scan; S replaced by carry-in state.
// ---------------------------------------------------------------------------
__global__ __launch_bounds__(256) void scanB_kernel(
    const float* __restrict__ P, float* __restrict__ S)
{
  const int gid = blockIdx.x*256 + threadIdx.x;
  const int n4 = gid & 3;
  const int d  = (gid >> 2) & (DI-1);
  const int b  = gid >> 13;

  float4 h = {0.f, 0.f, 0.f, 0.f};
  for (int c = 0; c < CHK; ++c) {
    const size_t idx = (((size_t)b*CHK + c)*DI + d)*NST + n4*4;
    float4 p = *(const float4*)(P + idx);
    float4 s = *(const float4*)(S + idx);
    *(float4*)(S + idx) = h;
    h.x = h.x*p.x + s.x;
    h.y = h.y*p.y + s.y;
    h.z = h.z*p.z + s.z;
    h.w = h.w*p.w + s.w;
  }
}

// ---------------------------------------------------------------------------
// Chunked scan, pass C: seeded local scan; y + skip + SiLU gate -> y_bf (bf16)
// ---------------------------------------------------------------------------
__global__ __launch_bounds__(256) void scanC_kernel(
    const unsigned short* __restrict__ uib,
    const float* __restrict__ dbc,
    const unsigned short* __restrict__ delta_bf,
    const float* __restrict__ A2tab,
    const float* __restrict__ Dp,
    const float* __restrict__ S,
    unsigned short* __restrict__ y_bf)
{
  const int bid = blockIdx.x;
  const int d   = (bid & 7)*256 + threadIdx.x;
  const int c   = (bid >> 3) & (CHK-1);
  const int b   = bid >> 9;

  float A2[NST];
  {
    const float4* ap = (const float4*)(A2tab + (size_t)d*NST);
#pragma unroll
    for (int q = 0; q < 4; ++q) {
      float4 v = ap[q];
      A2[q*4+0] = v.x; A2[q*4+1] = v.y; A2[q*4+2] = v.z; A2[q*4+3] = v.w;
    }
  }
  const float Dv = Dp[d];

  float h[NST];
  {
    const float* Sp = S + (((size_t)b*CHK + c)*DI + d)*NST;
#pragma unroll
    for (int q = 0; q < 4; ++q) {
      float4 sv = *(const float4*)(Sp + q*4);
      h[q*4+0] = sv.x; h[q*4+1] = sv.y; h[q*4+2] = sv.z; h[q*4+3] = sv.w;
    }
  }

  const int t0 = c * LCH;
  const unsigned short* dptr = delta_bf + ((size_t)b*SEQ + t0)*DI + d;
  const unsigned short* xptr = uib      + ((size_t)b*SEQ + t0)*4096 + d;
  const float* cptr          = dbc      + ((size_t)b*SEQ + t0)*96;
  unsigned short* yp         = y_bf     + ((size_t)b*SEQ + t0)*DI + d;

  float dt = bf2f(dptr[0]);
  float xv = bf2f(xptr[0]);
  float zv = bf2f(xptr[2048]);
  float4 Bv0 = *(const float4*)(cptr + 64);
  float4 Bv1 = *(const float4*)(cptr + 68);
  float4 Bv2 = *(const float4*)(cptr + 72);
  float4 Bv3 = *(const float4*)(cptr + 76);
  float4 Cv0 = *(const float4*)(cptr + 80);
  float4 Cv1 = *(const float4*)(cptr + 84);
  float4 Cv2 = *(const float4*)(cptr + 88);
  float4 Cv3 = *(const float4*)(cptr + 92);

  for (int t = 0; t < LCH; ++t) {
    const float dtc = dt, xvc = xv, zvc = zv;
    float Bc[NST] = {Bv0.x,Bv0.y,Bv0.z,Bv0.w, Bv1.x,Bv1.y,Bv1.z,Bv1.w,
                     Bv2.x,Bv2.y,Bv2.z,Bv2.w, Bv3.x,Bv3.y,Bv3.z,Bv3.w};
    float Cc[NST] = {Cv0.x,Cv0.y,Cv0.z,Cv0.w, Cv1.x,Cv1.y,Cv1.z,Cv1.w,
                     Cv2.x,Cv2.y,Cv2.z,Cv2.w, Cv3.x,Cv3.y,Cv3.z,Cv3.w};
    if (t + 1 < LCH) {
      const size_t tn = (size_t)(t+1);
      dt = bf2f(dptr[tn*DI]);
      xv = bf2f(xptr[tn*4096]);
      zv = bf2f(xptr[tn*4096 + 2048]);
      const float* cp = cptr + tn*96;
      Bv0 = *(const float4*)(cp + 64);
      Bv1 = *(const float4*)(cp + 68);
      Bv2 = *(const float4*)(cp + 72);
      Bv3 = *(const float4*)(cp + 76);
      Cv0 = *(const float4*)(cp + 80);
      Cv1 = *(const float4*)(cp + 84);
      Cv2 = *(const float4*)(cp + 88);
      Cv3 = *(const float4*)(cp + 92);
    }
    const float xdt = xvc * dtc;
    float y = 0.f;
#pragma unroll
    for (int nn = 0; nn < NST; ++nn) {
      float dA = fexp2(dtc * A2[nn]);
      h[nn] = h[nn]*dA + xdt*Bc[nn];
      y += h[nn]*Cc[nn];
    }
    y += xvc * Dv;
    y *= zvc / (1.f + fexp2(-1.44269504f * zvc));
    yp[(size_t)t*DI] = f2bf(y);
  }
}

// ---------------------------------------------------------------------------
extern "C" void kernel_launch(void* const* d_in, const int* in_sizes, int n_in,
                              void* d_out, int out_size, void* d_ws, size_t ws_size,
                              hipStream_t stream)
{
  const float* u     = (const float*)d_in[0];
  const float* W_in  = (const float*)d_in[1];
  const float* b_in  = (const float*)d_in[2];
  const float* W_x   = (const float*)d_in[3];
  const float* b_x   = (const float*)d_in[4];
  const float* W_dt  = (const float*)d_in[5];
  const float* b_dt  = (const float*)d_in[6];
  const float* A_log = (const float*)d_in[7];
  const float* Dp    = (const float*)d_in[8];
  const float* W_out = (const float*)d_in[9];
  const float* b_out = (const float*)d_in[10];
  float* out = (float*)d_out;

  // workspace (~94 MB total, all chunks 16B-aligned)
  unsigned short* ui_bf    = (unsigned short*)d_ws;             // MT*4096 u16
  float*          dbc      = (float*)(ui_bf + (size_t)MT*4096); // MT*96 f32
  unsigned short* delta_bf = (unsigned short*)(dbc + (size_t)MT*96);   // MT*DI u16
  unsigned short* y_bf     = delta_bf + (size_t)MT*DI;          // MT*DI u16
  unsigned short* wout_bf  = y_bf + (size_t)MT*DI;              // DM*DI u16
  unsigned short* wx_bf    = wout_bf + (size_t)DM*DI;           // 96*DI u16
  unsigned short* wdt_bf   = wx_bf + (size_t)96*DI;             // DI*64 u16
  unsigned short* draw_bf  = wdt_bf + (size_t)DI*64;            // MT*64 u16
  float*          S        = (float*)(draw_bf + (size_t)MT*64); // B*CHK*DI*NST f32
  float*          A2tab    = S + (size_t)BATCH*CHK*DI*NST;      // DI*NST f32
  float*          partial  = A2tab + (size_t)DI*NST;            // 4*MT*96 f32

  // d_out doubles as scratch: u_bf+Win_bf (dead after gemm1), then P, then out
  unsigned short* u_bf   = (unsigned short*)d_out;              // MT*DM u16
  unsigned short* win_bf = u_bf + (size_t)MT*DM;                // 2DI*DM u16
  float* P = (float*)d_out;                                     // B*CHK*DI*NST f32

  // 0) all fp32 -> bf16 conversions + A2 table, one launch
  convall_kernel<<<CUM5/256, 256, 0, stream>>>(
      u, W_in, W_out, W_x, W_dt, A_log,
      u_bf, win_bf, wout_bf, wx_bf, wdt_bf, A2tab);

  // 1) ui = u @ W_in^T + b_in   (M=4096, N=4096, K=1024) -> bf16.  BK=32 dbuf.
  gemm2_kernel<128, 32, true, 4096, 0><<<32*32, 256, 0, stream>>>(
      u_bf, win_bf, b_in, ui_bf, DM, 32);

  // 2) dbc partials (K-split x4) + reduce -> draw_bf (bf16) / dbc (f32)
  dbc_mfma_kernel<<<dim3(MT/64, 4), 256, 0, stream>>>(ui_bf, wx_bf, partial);
  dbc_reduce_kernel<<<MT*96/256, 256, 0, stream>>>(partial, b_x, dbc, draw_bf);

  // 3) delta = softplus(draw @ W_dt^T + b_dt)  (M=4096,N=2048,K=64) -> bf16
  gemm2_kernel<128, 32, true, 2048, 1><<<16*32, 256, 0, stream>>>(
      draw_bf, wdt_bf, b_dt, delta_bf, 64, 16);

  // 4) chunk-parallel selective scan (P overwrites u_bf/win_bf — dead now)
  scanA_kernel<<<BATCH*CHK*DI/256, 256, 0, stream>>>(ui_bf, dbc, delta_bf, A2tab, P, S);
  scanB_kernel<<<BATCH*DI*4/256, 256, 0, stream>>>(P, S);
  scanC_kernel<<<BATCH*CHK*DI/256, 256, 0, stream>>>(ui_bf, dbc, delta_bf, A2tab, Dp, S, y_bf);

  // 5) out = y @ W_out^T + b_out (M=4096, N=1024, K=2048) -> f32, BN=64, BK=64
  gemm2_kernel<64, 64, false, 1024, 0><<<16*32, 256, 0, stream>>>(
      y_bf, wout_bf, b_out, out, DI, 16);
}